// Round 3
// baseline (199.937 us; speedup 1.0000x reference)
//
#include <hip/hip_runtime.h>

#define NCAM 4
#define C 336
#define H 96
#define W 176
#define D 6
#define HB 240
#define WB 120
#define HW (H * W)        // 16896
#define CPB 112           // channels per block (3 parts)
#define WBPB 60           // wb per block (2 parts)
#define NCP 3
#define NWP 2

static __device__ __forceinline__ unsigned short f2bf(float f) {
    unsigned u = __float_as_uint(f);
    unsigned r = (u + 0x7fffu + ((u >> 16) & 1u)) >> 16;   // RNE
    return (unsigned short)r;
}

// ---------------------------------------------------------------------------
// Pass 1: feat[cam][c][h*w] (f32) -> tfeat[cam][h*w][c] (bf16)
// Tile 64 hw x 32 c. Loads: float4 along hw. Stores: uint4 (8 bf16) along c,
// one per thread -> 64B-per-4-lanes perfectly coalesced segments.
// ---------------------------------------------------------------------------
__global__ __launch_bounds__(256)
void vp_transpose_bf16(const float* __restrict__ in,
                       unsigned short* __restrict__ out) {
    __shared__ float tile[64][33];
    const int cam = blockIdx.z;
    const int hw0 = blockIdx.x * 64;     // 264 tiles, exact
    const int c0  = blockIdx.y * 32;     // 11 tiles, last has 16 valid c
    const int tid = threadIdx.x;

    // load: 2 float4 per thread (c rows cl and cl+16)
    const int hwq = tid & 15;            // 16 quads -> 64 hw
    const int cl  = tid >> 4;            // 0..15
    const float* src = in + (size_t)cam * C * HW + hw0 + hwq * 4;
#pragma unroll
    for (int cc = 0; cc < 2; ++cc) {
        const int c = c0 + cl + cc * 16;
        if (c < C) {
            const float4 v = *(const float4*)(src + (size_t)c * HW);
            tile[hwq * 4 + 0][cl + cc * 16] = v.x;
            tile[hwq * 4 + 1][cl + cc * 16] = v.y;
            tile[hwq * 4 + 2][cl + cc * 16] = v.z;
            tile[hwq * 4 + 3][cl + cc * 16] = v.w;
        }
    }
    __syncthreads();

    // store: 1 uint4 per thread = 8 bf16 along c
    const int hw  = tid >> 2;            // 0..63
    const int oct = tid & 3;             // c-octet
    const int cs  = c0 + oct * 8;
    if (cs < C) {
        uint4 r;
        unsigned* pr = (unsigned*)&r;
#pragma unroll
        for (int k = 0; k < 4; ++k) {
            unsigned lo = f2bf(tile[hw][oct * 8 + 2 * k]);
            unsigned hi = f2bf(tile[hw][oct * 8 + 2 * k + 1]);
            pr[k] = lo | (hi << 16);
        }
        *(uint4*)(out + (size_t)cam * HW * C + (size_t)(hw0 + hw) * C + cs) = r;
    }
}

// ---------------------------------------------------------------------------
// Pass 2: one block per (d, hb, cpart, wbpart): 112 channels x 60 wb.
// Wave owns 15 wb; lane = (cq, wbsub): cq<14 handles 8 channels (one uint4 =
// 8 bf16 per cam per wb). All 16 gathers preloaded into named registers
// (1 KB/lane in flight), then FMA, then direct scalar f32 stores to global
// (L2 merges the 4-wbi stores of each 64B line issued back-to-back).
// ---------------------------------------------------------------------------
__global__ __launch_bounds__(256, 4)
void vp_gather_bf16(const unsigned short* __restrict__ tfeat,
                    const int* __restrict__ pu, const int* __restrict__ pv,
                    const int* __restrict__ pvalid,
                    const float* __restrict__ pdens,
                    float* __restrict__ out) {
    __shared__ int   s_off[NCAM][WBPB];
    __shared__ float s_wgt[NCAM][WBPB];

    const int d      = blockIdx.x / HB;
    const int hb     = blockIdx.x % HB;
    const int cpart  = blockIdx.y % NCP;
    const int wbpart = blockIdx.y / NCP;
    const int wb0    = wbpart * WBPB;
    const int tid    = threadIdx.x;

    {
        const int i = tid;               // 240 needed, 256 threads
        if (i < NCAM * WBPB) {
            const int cam = i / WBPB, wbl = i % WBPB;
            const size_t pidx =
                ((size_t)(cam * D + d) * HB + hb) * WB + wb0 + wbl;
            s_wgt[cam][wbl] = pvalid[pidx] ? pdens[pidx] : 0.0f;
            s_off[cam][wbl] = cam * (HW * C) + (pv[pidx] * W + pu[pidx]) * C;
        }
    }
    __syncthreads();

    const int wave  = tid >> 6;
    const int lane  = tid & 63;
    const int cq    = lane >> 2;                 // 0..15, active < 14
    const int wbsub = lane & 3;
    const bool cact = (cq < 14);
    const int cqc   = cact ? cq : 13;            // clamp inactive lanes
    const int cbase = cpart * CPB + cqc * 8;

    // preload all 16 gathers (4 wbi x 4 cam)
    uint4 q[4][4];
    int wbc[4];
#pragma unroll
    for (int wbi = 0; wbi < 4; ++wbi) {
        const int wbl = wbsub + 4 * wbi;         // 0..15, active < 15
        wbc[wbi] = wave * 15 + (wbl < 15 ? wbl : 14);
#pragma unroll
        for (int cam = 0; cam < NCAM; ++cam) {
            q[wbi][cam] =
                *(const uint4*)(tfeat + (size_t)s_off[cam][wbc[wbi]] + cbase);
        }
    }

    float acc[4][8];
#pragma unroll
    for (int i = 0; i < 4; ++i)
#pragma unroll
        for (int j = 0; j < 8; ++j) acc[i][j] = 0.0f;

#pragma unroll
    for (int wbi = 0; wbi < 4; ++wbi) {
#pragma unroll
        for (int cam = 0; cam < NCAM; ++cam) {
            const float w = s_wgt[cam][wbc[wbi]];
            const uint4 v = q[wbi][cam];
            acc[wbi][0] += w * __uint_as_float(v.x << 16);
            acc[wbi][1] += w * __uint_as_float(v.x & 0xffff0000u);
            acc[wbi][2] += w * __uint_as_float(v.y << 16);
            acc[wbi][3] += w * __uint_as_float(v.y & 0xffff0000u);
            acc[wbi][4] += w * __uint_as_float(v.z << 16);
            acc[wbi][5] += w * __uint_as_float(v.z & 0xffff0000u);
            acc[wbi][6] += w * __uint_as_float(v.w << 16);
            acc[wbi][7] += w * __uint_as_float(v.w & 0xffff0000u);
        }
    }

    // direct scalar stores; 4-wbi stores of each 64B line issue back-to-back
#pragma unroll
    for (int wbi = 0; wbi < 4; ++wbi) {
        const int wbl = wbsub + 4 * wbi;
        if (cact && wbl < 15) {
            const int wb = wb0 + wave * 15 + wbl;
            float* po = out + (((size_t)d * C + cbase) * HB + hb) * WB + wb;
#pragma unroll
            for (int j = 0; j < 8; ++j)
                po[(size_t)j * HB * WB] = acc[wbi][j];
        }
    }
}

extern "C" void kernel_launch(void* const* d_in, const int* in_sizes, int n_in,
                              void* d_out, int out_size, void* d_ws,
                              size_t ws_size, hipStream_t stream) {
    const float* feat  = (const float*)d_in[0];
    const int* pu      = (const int*)d_in[1];
    const int* pv      = (const int*)d_in[2];
    const int* pvalid  = (const int*)d_in[3];
    const float* pdens = (const float*)d_in[4];
    float* out         = (float*)d_out;

    unsigned short* tfeat = (unsigned short*)d_ws;   // 45.4 MB

    dim3 tgrid(HW / 64, (C + 31) / 32, NCAM);
    vp_transpose_bf16<<<tgrid, 256, 0, stream>>>(feat, tfeat);

    dim3 ggrid(D * HB, NCP * NWP);
    vp_gather_bf16<<<ggrid, 256, 0, stream>>>(tfeat, pu, pv, pvalid, pdens,
                                              out);
}

// Round 4
// 182.569 us; speedup vs baseline: 1.0951x; 1.0951x over previous
//
#include <hip/hip_runtime.h>

#define NCAM 4
#define C 336
#define H 96
#define W 176
#define D 6
#define HB 240
#define WB 120
#define HW (H * W)        // 16896
#define WBPB 60           // wb per block (2 parts)
#define NWP 2

static __device__ __forceinline__ unsigned short f2bf(float f) {
    unsigned u = __float_as_uint(f);
    unsigned r = (u + 0x7fffu + ((u >> 16) & 1u)) >> 16;   // RNE
    return (unsigned short)r;
}

// ---------------------------------------------------------------------------
// Pass 1: feat[cam][c][h*w] (f32) -> tfeat[cam][h*w][c] (bf16)
// Tile 64 hw x 32 c; float4 loads along hw, one uint4 (8 bf16) store per
// thread along c. (measured ~26 us, near 136 MB / 6.3 TB/s roofline)
// ---------------------------------------------------------------------------
__global__ __launch_bounds__(256)
void vp_transpose_bf16(const float* __restrict__ in,
                       unsigned short* __restrict__ out) {
    __shared__ float tile[64][33];
    const int cam = blockIdx.z;
    const int hw0 = blockIdx.x * 64;
    const int c0  = blockIdx.y * 32;
    const int tid = threadIdx.x;

    const int hwq = tid & 15;
    const int cl  = tid >> 4;
    const float* src = in + (size_t)cam * C * HW + hw0 + hwq * 4;
#pragma unroll
    for (int cc = 0; cc < 2; ++cc) {
        const int c = c0 + cl + cc * 16;
        if (c < C) {
            const float4 v = *(const float4*)(src + (size_t)c * HW);
            tile[hwq * 4 + 0][cl + cc * 16] = v.x;
            tile[hwq * 4 + 1][cl + cc * 16] = v.y;
            tile[hwq * 4 + 2][cl + cc * 16] = v.z;
            tile[hwq * 4 + 3][cl + cc * 16] = v.w;
        }
    }
    __syncthreads();

    const int hw  = tid >> 2;
    const int oct = tid & 3;
    const int cs  = c0 + oct * 8;
    if (cs < C) {
        uint4 r;
        unsigned* pr = (unsigned*)&r;
#pragma unroll
        for (int k = 0; k < 4; ++k) {
            unsigned lo = f2bf(tile[hw][oct * 8 + 2 * k]);
            unsigned hi = f2bf(tile[hw][oct * 8 + 2 * k + 1]);
            pr[k] = lo | (hi << 16);
        }
        *(uint4*)(out + (size_t)cam * HW * C + (size_t)(hw0 + hw) * C + cs) = r;
    }
}

// ---------------------------------------------------------------------------
// Pass 2: one block per (d, hb, wbpart): ALL 336 channels x 60 wb.
// 3 c-parts of 112 channels looped INSIDE the block so each random 672B
// column is read contiguously (boundary lines stay L2-hot) and proj is
// staged once. Lane map: cq = lane&15 (<14 active, 8 ch = one uint4),
// wbsub = lane>>4; wave owns 15 wb. Next cpart's 16 loads are issued
// before the current cpart's LDS store phase (loads into VGPRs don't
// drain at barriers -> they overlap the dump/store sweeps).
// Stores: proven R2 path - LDS-staged full-row sweeps (exact 227MB write).
// ---------------------------------------------------------------------------
__global__ __launch_bounds__(256, 4)
void vp_gather_bf16(const unsigned short* __restrict__ tfeat,
                    const int* __restrict__ pu, const int* __restrict__ pv,
                    const int* __restrict__ pvalid,
                    const float* __restrict__ pdens,
                    float* __restrict__ out) {
    __shared__ int   s_off[NCAM][WBPB];
    __shared__ float s_wgt[NCAM][WBPB];
    __shared__ float s_acc[56][61];

    const int d   = blockIdx.x / HB;
    const int hb  = blockIdx.x % HB;
    const int wb0 = blockIdx.y * WBPB;
    const int tid = threadIdx.x;

    if (tid < NCAM * WBPB) {
        const int cam = tid / WBPB, wbl = tid % WBPB;
        const size_t pidx = ((size_t)(cam * D + d) * HB + hb) * WB + wb0 + wbl;
        s_wgt[cam][wbl] = pvalid[pidx] ? pdens[pidx] : 0.0f;
        s_off[cam][wbl] = cam * (HW * C) + (pv[pidx] * W + pu[pidx]) * C;
    }
    __syncthreads();

    const int wave  = tid >> 6;
    const int lane  = tid & 63;
    const int cq    = lane & 15;               // active < 14
    const int wbsub = lane >> 4;               // 0..3
    const bool cact = (cq < 14);
    const int coff  = (cact ? cq : 13) * 8;    // element offset of c-octet

    int wbc[4];
#pragma unroll
    for (int wbi = 0; wbi < 4; ++wbi) {
        const int wbl = wbsub + 4 * wbi;       // 0..15, active < 15
        wbc[wbi] = wave * 15 + (wbl < 15 ? wbl : 14);
    }

    // initial load batch (cpart 0)
    uint4 q[4][4];
#pragma unroll
    for (int wbi = 0; wbi < 4; ++wbi)
#pragma unroll
        for (int cam = 0; cam < NCAM; ++cam)
            q[wbi][cam] = *(const uint4*)(tfeat +
                (size_t)(unsigned)(s_off[cam][wbc[wbi]] + coff));

#pragma unroll
    for (int cp = 0; cp < 3; ++cp) {
        float acc[4][8];
#pragma unroll
        for (int i = 0; i < 4; ++i)
#pragma unroll
            for (int j = 0; j < 8; ++j) acc[i][j] = 0.0f;

#pragma unroll
        for (int wbi = 0; wbi < 4; ++wbi) {
#pragma unroll
            for (int cam = 0; cam < NCAM; ++cam) {
                const float w = s_wgt[cam][wbc[wbi]];
                const uint4 v = q[wbi][cam];
                acc[wbi][0] += w * __uint_as_float(v.x << 16);
                acc[wbi][1] += w * __uint_as_float(v.x & 0xffff0000u);
                acc[wbi][2] += w * __uint_as_float(v.y << 16);
                acc[wbi][3] += w * __uint_as_float(v.y & 0xffff0000u);
                acc[wbi][4] += w * __uint_as_float(v.z << 16);
                acc[wbi][5] += w * __uint_as_float(v.z & 0xffff0000u);
                acc[wbi][6] += w * __uint_as_float(v.w << 16);
                acc[wbi][7] += w * __uint_as_float(v.w & 0xffff0000u);
            }
        }

        // prefetch next cpart while the store phase runs
        if (cp < 2) {
#pragma unroll
            for (int wbi = 0; wbi < 4; ++wbi)
#pragma unroll
                for (int cam = 0; cam < NCAM; ++cam)
                    q[wbi][cam] = *(const uint4*)(tfeat +
                        (size_t)(unsigned)(s_off[cam][wbc[wbi]] + coff +
                                           (cp + 1) * 112));
        }

        // dump + store, two halves of 56 c-rows
#pragma unroll
        for (int half = 0; half < 2; ++half) {
            if (cact && cq >= half * 7 && cq < half * 7 + 7) {
                const int rbase = (cq - half * 7) * 8;
#pragma unroll
                for (int wbi = 0; wbi < 4; ++wbi) {
                    const int wbl = wbsub + 4 * wbi;
                    if (wbl < 15) {
#pragma unroll
                        for (int j = 0; j < 8; ++j)
                            s_acc[rbase + j][wave * 15 + wbl] = acc[wbi][j];
                    }
                }
            }
            __syncthreads();

            // sweep: float2 along wb, 60 wb x 56 rows
            const int wp = tid & 31;           // active < 30
            const int rb = tid >> 5;           // 0..7
            if (wp < 30) {
#pragma unroll
                for (int k = 0; k < 7; ++k) {
                    const int r = rb + 8 * k;
                    const int c = cp * 112 + half * 56 + r;
                    float2 v;
                    v.x = s_acc[r][wp * 2 + 0];
                    v.y = s_acc[r][wp * 2 + 1];
                    *(float2*)(out + (((size_t)d * C + c) * HB + hb) * WB +
                               wb0 + wp * 2) = v;
                }
            }
            __syncthreads();
        }
    }
}

extern "C" void kernel_launch(void* const* d_in, const int* in_sizes, int n_in,
                              void* d_out, int out_size, void* d_ws,
                              size_t ws_size, hipStream_t stream) {
    const float* feat  = (const float*)d_in[0];
    const int* pu      = (const int*)d_in[1];
    const int* pv      = (const int*)d_in[2];
    const int* pvalid  = (const int*)d_in[3];
    const float* pdens = (const float*)d_in[4];
    float* out         = (float*)d_out;

    unsigned short* tfeat = (unsigned short*)d_ws;   // 45.4 MB

    dim3 tgrid(HW / 64, (C + 31) / 32, NCAM);
    vp_transpose_bf16<<<tgrid, 256, 0, stream>>>(feat, tfeat);

    dim3 ggrid(D * HB, NWP);
    vp_gather_bf16<<<ggrid, 256, 0, stream>>>(tfeat, pu, pv, pvalid, pdens,
                                              out);
}